// Round 2
// 2432.511 us; speedup vs baseline: 1.3013x; 1.3013x over previous
//
#include <hip/hip_runtime.h>
#include <stdint.h>

#define TT 512
#define BB 256
#define HH 512
#define NOUTC 64
// 16 groups x 16 blocks; group g = blocks {g, g+16, ...} (co-XCD by residue).
// R8: R7 design with ws footprint restored to the known-good 540,672 B
// (per-wave flags packed at 16B stride, 16KB total) and x-prefetch issued
// after the flag store so the publish->flag path drains only the h store.
// Per-wave publish/flags (64 flags/group), cell update in registers via
// shfl_xor(32) (A-rows remapped: tile0={i,f}x8h, tile1={g,o}x8h), classifier
// in the poll slack on wave0 of s<4 blocks.

typedef _Float16 f16;
typedef f16 f16x8 __attribute__((ext_vector_type(8)));
typedef float f32x4 __attribute__((ext_vector_type(4)));
typedef unsigned long long ull;

__device__ __forceinline__ float sigmoidf_(float x) {
  x = fminf(fmaxf(x, -30.f), 30.f);
  return 1.f / (1.f + __expf(-x));
}
__device__ __forceinline__ float tanhf_(float x) {
  x = fminf(fmaxf(x, -15.f), 15.f);
  float e = __expf(2.f * x);
  return (e - 1.f) / (e + 1.f);
}

__device__ __forceinline__ f16x8 cvt8(const float* __restrict__ src) {
  float4 p0 = *(const float4*)(src);
  float4 p1 = *(const float4*)(src + 4);
  f16x8 a;
  a[0] = (f16)p0.x; a[1] = (f16)p0.y; a[2] = (f16)p0.z; a[3] = (f16)p0.w;
  a[4] = (f16)p1.x; a[5] = (f16)p1.y; a[6] = (f16)p1.z; a[7] = (f16)p1.w;
  return a;
}

__global__ void zero_ws(uint32_t* __restrict__ ws, int nws) {
  int idx = blockIdx.x * blockDim.x + threadIdx.x;
  int stride = gridDim.x * blockDim.x;
  for (int i = idx; i < nws; i += stride) ws[i] = 0u;
}

__global__ __launch_bounds__(256, 1) void lstm_kernel(
    const float* __restrict__ input, const float* __restrict__ dtp,
    const float* __restrict__ W_ih, const float* __restrict__ W_hh,
    const float* __restrict__ b_ih, const float* __restrict__ b_hh,
    const float* __restrict__ W_cls, const float* __restrict__ b_cls,
    float* __restrict__ out, uint32_t* __restrict__ flg,
    f16* __restrict__ h_buf) {
  __shared__ __align__(16) f16 xh[16][648];      // [batch n][128 x | 512 h]
  __shared__ __align__(16) f16x8 wlds[16][64];   // W_cls frags (cls blocks)

  const int tid = threadIdx.x;
  const int g = blockIdx.x & 15;   // group: batch slice [g*16, g*16+16)
  const int s = blockIdx.x >> 4;   // sub: hidden slice [s*32, s*32+32)
  const int b0 = g * 16;
  const int w = tid >> 6;          // wave id 0..3
  const int lane = tid & 63;
  const int l = lane & 15;
  const int quad = lane >> 4;
  const int mt_o = s & 3;
  const bool cls_block = (s < 4);
  const int hb = s * 32 + w * 8;   // wave's 8-hidden slice base

  // ---- A-fragments: m-tile0 rows = {i-gate h hb..+7, f-gate h hb..+7},
  //      m-tile1 = {g,o}. A[m=l][k=quad*8+j]; 20 K-chunks (128 x | 512 h).
  // D (acc) mapping: m=quad*4+r -> gate m>>3, h = hb + (m&7); col n = l.
  f16x8 afrag[2][20];
#pragma unroll
  for (int mp = 0; mp < 2; ++mp) {
    const int grow = (mp * 2 + (l >> 3)) * HH + hb + (l & 7);
#pragma unroll
    for (int it = 0; it < 20; ++it) {
      const int kb = it * 32 + quad * 8;
      const float* src = (kb < 128) ? (W_ih + (size_t)grow * 128 + kb)
                                    : (W_hh + (size_t)grow * HH + (kb - 128));
      afrag[mp][it] = cvt8(src);
    }
  }

  // ---- cell biases (used by quad<2 lanes): h = hb + (quad&1)*4 + r
  float bi[4], bf[4], bg[4], bo[4];
  {
    const int hg = hb + (quad & 1) * 4;
#pragma unroll
    for (int r = 0; r < 4; ++r) {
      bi[r] = b_ih[0 * HH + hg + r] + b_hh[0 * HH + hg + r];
      bf[r] = b_ih[1 * HH + hg + r] + b_hh[1 * HH + hg + r];
      bg[r] = b_ih[2 * HH + hg + r] + b_hh[2 * HH + hg + r];
      bo[r] = b_ih[3 * HH + hg + r] + b_hh[3 * HH + hg + r];
    }
  }

  // ---- classifier state (wave0 of s<4 blocks): o-tile mt_o, n=batch, K=512
  float bcls4[4] = {0.f, 0.f, 0.f, 0.f};
  if (cls_block && w == 0) {
#pragma unroll
    for (int r = 0; r < 4; ++r) bcls4[r] = b_cls[mt_o * 16 + quad * 4 + r];
#pragma unroll
    for (int it = 0; it < 16; ++it)
      wlds[it][lane] =
          cvt8(W_cls + (size_t)(mt_o * 16 + l) * HH + it * 32 + quad * 8);
  }

  auto classify = [&](int tt) {
    f32x4 oa = {0.f, 0.f, 0.f, 0.f}, ob = {0.f, 0.f, 0.f, 0.f};
#pragma unroll
    for (int it = 0; it < 16; it += 2) {
      f16x8 ba = *(const f16x8*)(&xh[l][128 + it * 32 + quad * 8]);
      f16x8 bb = *(const f16x8*)(&xh[l][128 + (it + 1) * 32 + quad * 8]);
      oa = __builtin_amdgcn_mfma_f32_16x16x32_f16(wlds[it][lane], ba, oa, 0, 0, 0);
      ob = __builtin_amdgcn_mfma_f32_16x16x32_f16(wlds[it + 1][lane], bb, ob, 0, 0, 0);
    }
    float4 o;
    o.x = oa[0] + ob[0] + bcls4[0];
    o.y = oa[1] + ob[1] + bcls4[1];
    o.z = oa[2] + ob[2] + bcls4[2];
    o.w = oa[3] + ob[3] + bcls4[3];
    *(float4*)(out + ((size_t)tt * BB + b0 + l) * NOUTC + mt_o * 16 +
               quad * 4) = o;
  };

  // ---- prologue: zero h-region of xh, stage x_0
#pragma unroll
  for (int ci = 0; ci < 8; ++ci) {
    const int c2 = ci * 256 + tid;
    *(ull*)(&xh[c2 >> 7][128 + (c2 & 127) * 4]) = 0ull;
  }
  const int kx = tid & 127;   // thread's fixed x column
  const int nx0 = tid >> 7;
#pragma unroll
  for (int ii = 0; ii < 8; ++ii) {
    const int row = b0 + ii * 2 + nx0;
    float v = (kx < 127) ? input[(size_t)row * 127 + kx] : dtp[row];
    xh[ii * 2 + nx0][kx] = (f16)v;
  }
  float cc[4] = {0.f, 0.f, 0.f, 0.f};
  __syncthreads();

  for (int t = 0; t < TT; ++t) {
    // ---- gates: [4 gates x 8 hid] x [16 batch], K = 640
    f32x4 acc0 = {0.f, 0.f, 0.f, 0.f}, acc1 = {0.f, 0.f, 0.f, 0.f};
#pragma unroll
    for (int it = 0; it < 20; ++it) {
      f16x8 b = *(const f16x8*)(&xh[l][it * 32 + quad * 8]);
      acc0 = __builtin_amdgcn_mfma_f32_16x16x32_f16(afrag[0][it], b, acc0, 0, 0, 0);
      acc1 = __builtin_amdgcn_mfma_f32_16x16x32_f16(afrag[1][it], b, acc1, 0, 0, 0);
    }

    // ---- cell update in regs: quad<2 holds i (acc0) and g (acc1);
    //      f,o come from lane^32 (quad+2). All lanes run the shuffles.
    float fsh[4], osh[4];
#pragma unroll
    for (int r = 0; r < 4; ++r) {
      fsh[r] = __shfl_xor(acc0[r], 32, 64);
      osh[r] = __shfl_xor(acc1[r], 32, 64);
    }
    if (quad < 2) {
      union { f16 h4[4]; ull u; } pk;
#pragma unroll
      for (int r = 0; r < 4; ++r) {
        float vi = acc0[r] + bi[r];
        float vf = fsh[r] + bf[r];
        float vg = acc1[r] + bg[r];
        float vo = osh[r] + bo[r];
        float iv = sigmoidf_(vi), fv = sigmoidf_(vf);
        float gv = tanhf_(vg), ov = sigmoidf_(vo);
        cc[r] = fv * cc[r] + iv * gv;
        pk.h4[r] = (f16)(ov * tanhf_(cc[r]));
      }
      // publish this wave's 8B chunk: h_buf[t&1][g][l][hb + quad*4 .. +4)
      __hip_atomic_store(
          (ull*)(h_buf + (size_t)(((t & 1) * 16) + g) * (16 * HH) +
                 (size_t)l * HH + hb + quad * 4),
          pk.u, __ATOMIC_RELAXED, __HIP_MEMORY_SCOPE_AGENT);
    }
    // wave-local drain (only the publish store is outstanding), then this
    // wave's flag — no block-wide barrier on the publish path.
    asm volatile("s_waitcnt vmcnt(0)" ::: "memory");
    if (lane == 0)
      __hip_atomic_store(flg + (size_t)(g * 64 + s * 4 + w) * 4,
                         (uint32_t)(t + 1), __ATOMIC_RELAXED,
                         __HIP_MEMORY_SCOPE_AGENT);
    __syncthreads();  // Bx: all waves done reading xh this step

    // ---- prefetch x_{t+1} into regs (latency hides under classify/poll)
    float xf[8];
    if (t + 1 < TT) {
#pragma unroll
      for (int ii = 0; ii < 8; ++ii) {
        const int row = (t + 1) * BB + b0 + ii * 2 + nx0;
        xf[ii] = (kx < 127) ? input[(size_t)row * 127 + kx] : dtp[row];
      }
    }

    // ---- classifier out[t-1] in the poll slack (xh h-region = h_{t-1})
    if (t > 0 && cls_block && w == 0) classify(t - 1);

    // ---- write prefetched x_{t+1} into xh x-region
    if (t + 1 < TT) {
#pragma unroll
      for (int ii = 0; ii < 8; ++ii) xh[ii * 2 + nx0][kx] = (f16)xf[ii];
    }

    // ---- wave1: ballot-poll all 64 per-wave flags of the group
    if (w == 1) {
      const uint32_t* fp = flg + (size_t)(g * 64 + lane) * 4;
      for (;;) {
        uint32_t v = __hip_atomic_load(fp, __ATOMIC_RELAXED,
                                       __HIP_MEMORY_SCOPE_AGENT);
        if (__ballot(v >= (uint32_t)(t + 1)) == ~0ull) break;
        __builtin_amdgcn_s_sleep(1);
      }
    }
    __syncthreads();  // B1: h_t ready everywhere

    // ---- stage h_t into xh[:,128:640] (16 rows x 128 8B chunks)
    {
      const ull* hbp =
          (const ull*)(h_buf + (size_t)(((t & 1) * 16) + g) * (16 * HH));
#pragma unroll
      for (int ci = 0; ci < 8; ++ci) {
        const int c2 = ci * 256 + tid;
        ull v = __hip_atomic_load(hbp + (size_t)(c2 >> 7) * 128 + (c2 & 127),
                                  __ATOMIC_RELAXED, __HIP_MEMORY_SCOPE_AGENT);
        *(ull*)(&xh[c2 >> 7][128 + (c2 & 127) * 4]) = v;
      }
    }
    __syncthreads();  // B2
  }

  // final output row uses h_{TT-1} (staged on the last iteration)
  if (cls_block && w == 0) classify(TT - 1);
}

extern "C" void kernel_launch(void* const* d_in, const int* in_sizes, int n_in,
                              void* d_out, int out_size, void* d_ws,
                              size_t ws_size, hipStream_t stream) {
  const float* input = (const float*)d_in[0];
  const float* dtp = (const float*)d_in[1];
  const float* W_ih = (const float*)d_in[2];
  const float* W_hh = (const float*)d_in[3];
  const float* b_ih = (const float*)d_in[4];
  const float* b_hh = (const float*)d_in[5];
  const float* W_cls = (const float*)d_in[6];
  const float* b_cls = (const float*)d_in[7];
  float* out = (float*)d_out;

  // ws layout: [0, 16K): 1024 per-wave flags at 16B stride;
  //            [16K, 16K+512K): h double-buffer [2][16][16][512] f16
  // total 540,672 B == the footprint of the last harness-verified kernel.
  uint32_t* flg = (uint32_t*)d_ws;
  f16* h_buf = (f16*)((char*)d_ws + 16384);
  const int nws_words = (16384 + 2 * 16 * 16 * HH * 2) / 4;  // 135168

  zero_ws<<<256, 256, 0, stream>>>(flg, nws_words);
  lstm_kernel<<<256, 256, 0, stream>>>(input, dtp, W_ih, W_hh, b_ih, b_hh,
                                       W_cls, b_cls, out, flg, h_buf);
}